// Round 2
// baseline (367.737 us; speedup 1.0000x reference)
//
#include <hip/hip_runtime.h>
#include <math.h>

// B=64, H=1024, I=512. out[b,o] = tanh( dot(x[b,:],W_ih[o,:]) + b_ih[o]
//                                       + softmax_h(W_hh[o,:]/tau + g[b,o,:]) . h_prev[b,:] )
//
// R5 == R4 resubmission (R4 hit broker "container failed twice" infra error;
// kernel never ran).
//
// R4 rationale: dur_us=364 is NOT the kernel (kernel absent from rocprof
// top-5; all >=157us dispatches are 1-GiB harness fills at ~6.7 TB/s).
// Kernel is <157us on-device. Obligatory traffic = gumbel 268 MB ->
// 42.6 us floor. This round attacks the one remaining inefficiency
// candidate: gumbel's 268 MB stream thrashing L2 (4 MB/XCD) / L3 (256 MB)
// and forcing W_hh (64x reuse/row), W_ih and h_prev re-reads out to HBM
// (~900 MB worst case).
//   1) gumbel loads are non-temporal (nt): read-once data must not evict
//      the reused operands. No cross-iteration gumbel reuse exists anyway —
//      the 1-GiB poison fills flush L3 between timed iterations.
//   2) block-shares-o: the 4 waves of a block handle the SAME o for 4
//      consecutive b. W_hh[o,:] and W_ih[o,:] are fetched once per block
//      (L1 broadcast across waves) instead of once per wave -> 4x less
//      re-read traffic; L2 working set shrinks to the live W_hh rows.
// Numerics unchanged: streaming no-max softmax (logits bounded: gumbel in
// [-2.92, 18.42], W_hh/tau ~ +-0.1 -> exp < 1.2e8, fp32 sum < 1.2e11).

constexpr int B_ = 64;
constexpr int H_ = 1024;
constexpr int I_ = 512;

typedef float f32x4 __attribute__((ext_vector_type(4)));

__global__ __launch_bounds__(256) void reservoir_fused_kernel(
    const float* __restrict__ x_t,         // (B, I)
    const float* __restrict__ h_prev,      // (B, H)
    const float* __restrict__ W_ih,        // (H, I)
    const float* __restrict__ b_ih,        // (H,)
    const float* __restrict__ W_hh,        // (H, H)
    const float* __restrict__ temperature, // scalar
    const float* __restrict__ gumbel,      // (B, H, H)
    float* __restrict__ out)               // (B, H)
{
    const int lane = threadIdx.x & 63;
    const int wk   = threadIdx.x >> 6;                 // wave-in-block: 0..3
    const int o    = blockIdx.x & (H_ - 1);            // shared by all 4 waves
    const int b    = ((blockIdx.x >> 10) << 2) + wk;   // 4 consecutive b per block

    const float tau = fmaxf(temperature[0], 1e-3f);
    const float inv_tau = 1.0f / tau;

    // ---- input contribution partial: dot(x[b,:], W_ih[o,:]), 8 elems/lane ----
    // W_ih row is shared by the 4 waves of the block -> one L1 fill.
    float ic = 0.0f;
    {
        const f32x4* x4 = reinterpret_cast<const f32x4*>(x_t + (size_t)b * I_);
        const f32x4* w4 = reinterpret_cast<const f32x4*>(W_ih + (size_t)o * I_);
#pragma unroll
        for (int c = 0; c < I_ / 256; ++c) {   // 2 iters
            f32x4 xv = x4[c * 64 + lane];
            f32x4 wv = w4[c * 64 + lane];
            ic = fmaf(xv[0], wv[0], ic);
            ic = fmaf(xv[1], wv[1], ic);
            ic = fmaf(xv[2], wv[2], ic);
            ic = fmaf(xv[3], wv[3], ic);
        }
    }

    // ---- streaming exp-sum and weighted sum over the 1024-wide row ----
    // gumbel: read-once stream -> non-temporal (keep L2/L3 for W_hh/h_prev).
    // W_hh row: shared by the 4 waves -> one L1 fill, temporal.
    // h_prev row: 256 KB total across all b -> L2-resident, temporal.
    float s = 0.0f, t = 0.0f;
    {
        const f32x4* g4 = reinterpret_cast<const f32x4*>(gumbel + ((size_t)b * H_ + o) * H_);
        const f32x4* w4 = reinterpret_cast<const f32x4*>(W_hh + (size_t)o * H_);
        const f32x4* h4 = reinterpret_cast<const f32x4*>(h_prev + (size_t)b * H_);
#pragma unroll
        for (int c = 0; c < 4; ++c) {
            f32x4 g = __builtin_nontemporal_load(&g4[c * 64 + lane]);
            f32x4 w = w4[c * 64 + lane];
            f32x4 h = h4[c * 64 + lane];
            float e0 = __expf(fmaf(w[0], inv_tau, g[0]));
            float e1 = __expf(fmaf(w[1], inv_tau, g[1]));
            float e2 = __expf(fmaf(w[2], inv_tau, g[2]));
            float e3 = __expf(fmaf(w[3], inv_tau, g[3]));
            s += (e0 + e1) + (e2 + e3);
            t = fmaf(e0, h[0], t);
            t = fmaf(e1, h[1], t);
            t = fmaf(e2, h[2], t);
            t = fmaf(e3, h[3], t);
        }
    }

    // ---- wave-wide sums: s, t, ic together (interleaved for ILP) ----
#pragma unroll
    for (int off = 32; off > 0; off >>= 1) {
        s  += __shfl_xor(s,  off, 64);
        t  += __shfl_xor(t,  off, 64);
        ic += __shfl_xor(ic, off, 64);
    }

    if (lane == 0) {
        float res = tanhf(ic + b_ih[o] + t / s);
        out[(size_t)b * H_ + o] = res;
    }
}

extern "C" void kernel_launch(void* const* d_in, const int* in_sizes, int n_in,
                              void* d_out, int out_size, void* d_ws, size_t ws_size,
                              hipStream_t stream) {
    const float* x_t    = (const float*)d_in[0];
    const float* h_prev = (const float*)d_in[1];
    const float* W_ih   = (const float*)d_in[2];
    const float* b_ih   = (const float*)d_in[3];
    const float* W_hh   = (const float*)d_in[4];
    const float* temp   = (const float*)d_in[5];
    const float* gum    = (const float*)d_in[6];
    float* out = (float*)d_out;

    const int blocks = (B_ / 4) * H_;   // 16384 blocks x 256 threads = 65536 waves
    reservoir_fused_kernel<<<blocks, 256, 0, stream>>>(
        x_t, h_prev, W_ih, b_ih, W_hh, temp, gum, out);
}